// Round 1
// baseline (719.546 us; speedup 1.0000x reference)
//
#include <hip/hip_runtime.h>
#include <hip/hip_fp16.h>

// Euler neural-ODE scan: B=1024, L=512, S=64, U=32, H=512, dt=0.1.
// 64 blocks x 512 threads (8 waves). Block owns 16 batch rows for all 512 steps.
// GEMM1: z(16x192 split-f16) @ W1ext(192x512) via mfma_f32_16x16x32_f16,
//   wave w owns H-cols [64w,64w+64), W1 fragments live in registers.
// GEMM2: h(16x512) @ W2(512x64), wave (ks,ns): K-half ks, S-cols [16ns,16ns+16),
//   W2 fragments in registers, K-pair reduced through LDS.
// State kept in fp32 (C-fragment layout) in waves ks==0; written to LDS as
// hi/lo f16 pair each step (split-f16 => ~2^-21 effective relative error).
// u prefetched one step ahead (reg-staged) and written hi/lo to LDS.

typedef _Float16 f16;
typedef __attribute__((ext_vector_type(8))) _Float16 f16x8;
typedef __attribute__((ext_vector_type(4))) float f32x4;

#define MFMA16(a, b, c) __builtin_amdgcn_mfma_f32_16x16x32_f16((a), (b), (c), 0, 0, 0)

__device__ __forceinline__ float tanh_fast(float x) {
    // tanh(x) = 1 - 2/(1+e^{2x}); v_exp_f32 computes 2^x natively.
    float t = __builtin_amdgcn_exp2f(x * 2.885390081777927f);  // e^{2x}
    float r = __builtin_amdgcn_rcpf(t + 1.0f);
    return __builtin_fmaf(-2.0f, r, 1.0f);
    // x >> 0: t=inf -> r=0 -> 1.  x << 0: t=0 -> r=1 -> -1.  Correct limits.
}

__global__ __launch_bounds__(512, 2)
void euler_kernel(const float* __restrict__ init,
                  const float* __restrict__ uin,
                  const float* __restrict__ W1,
                  const float* __restrict__ b1,
                  const float* __restrict__ W2,
                  const float* __restrict__ b2,
                  float* __restrict__ out) {
    const int L = 512, S = 64, U = 32, H = 512;
    const int tid  = threadIdx.x;
    const int lane = tid & 63;
    const int w    = tid >> 6;      // wave 0..7
    const int g    = lane >> 4;     // lane group 0..3 (k-groups of MFMA frags)
    const int r16  = lane & 15;
    const int ks   = w >> 2;        // GEMM2 K-half
    const int ns   = w & 3;         // GEMM2 N-slice (16 cols of S)
    const int ncol0 = w * 64;       // GEMM1 N-slice base (64 cols of H)
    const int b0   = blockIdx.x * 16;

    // z layout along K=192: [state_hi(64) | state_lo(64) | u_hi(32) | u_lo(32)]
    __shared__ f16  zbuf[16][200];   // +8 pad
    __shared__ f16  hbuf[16][520];   // +8 pad
    __shared__ float redbuf[4][256]; // GEMM2 K-pair reduction

    // ---- one-time register staging of weights (B-fragments) ----
    f16x8 W1F[6][4];
    #pragma unroll
    for (int kk = 0; kk < 6; ++kk)
      #pragma unroll
      for (int nf = 0; nf < 4; ++nf)
        #pragma unroll
        for (int j = 0; j < 8; ++j) {
            int k  = kk * 32 + g * 8 + j;
            int kr = (k < 128) ? (k & 63) : (64 + (k & 31));  // hi/lo share W1 rows
            W1F[kk][nf][j] = (f16)W1[kr * H + ncol0 + nf * 16 + r16];
        }
    f16x8 W2F[8];
    #pragma unroll
    for (int kk = 0; kk < 8; ++kk)
      #pragma unroll
      for (int j = 0; j < 8; ++j) {
          int k = ks * 256 + kk * 32 + g * 8 + j;
          W2F[kk][j] = (f16)W2[k * S + ns * 16 + r16];
      }
    float b1v[4];
    #pragma unroll
    for (int nf = 0; nf < 4; ++nf) b1v[nf] = b1[ncol0 + nf * 16 + r16];
    const float b2v = b2[ns * 16 + r16];

    // ---- state / u prologue ----
    float stateF[4] = {0.f, 0.f, 0.f, 0.f};
    float ua = 0.f, ub = 0.f;
    int urow = 0, ucol = 0;
    if (ks == 0) {
        #pragma unroll
        for (int j = 0; j < 4; ++j) {
            float s = init[(size_t)(b0 + g * 4 + j) * S + ns * 16 + r16];
            stateF[j] = s;
            f16 sh = (f16)s;
            zbuf[g * 4 + j][ns * 16 + r16]      = sh;
            zbuf[g * 4 + j][64 + ns * 16 + r16] = (f16)(s - (float)sh);
        }
    } else {
        urow = ns * 4 + (lane >> 4);
        ucol = 2 * (lane & 15);
        const float* up = uin + (size_t)(b0 + urow) * L * U + ucol;  // t = 0
        float a = up[0], b = up[1];
        f16 ah = (f16)a, bh = (f16)b;
        zbuf[urow][128 + ucol]     = ah;
        zbuf[urow][128 + ucol + 1] = bh;
        zbuf[urow][160 + ucol]     = (f16)(a - (float)ah);
        zbuf[urow][160 + ucol + 1] = (f16)(b - (float)bh);
        ua = up[U]; ub = up[U + 1];  // prefetch t = 1
    }
    __syncthreads();

    #pragma unroll 1
    for (int t = 0; t < L; ++t) {
        // ---- phase 1: GEMM1 + tanh + h -> LDS ----
        f16x8 zf[6];
        #pragma unroll
        for (int kk = 0; kk < 6; ++kk)
            zf[kk] = *(const f16x8*)&zbuf[r16][kk * 32 + g * 8];
        f32x4 acc1[4];
        #pragma unroll
        for (int nf = 0; nf < 4; ++nf)
            acc1[nf] = (f32x4){b1v[nf], b1v[nf], b1v[nf], b1v[nf]};
        #pragma unroll
        for (int kk = 0; kk < 6; ++kk)
          #pragma unroll
          for (int nf = 0; nf < 4; ++nf)
            acc1[nf] = MFMA16(zf[kk], W1F[kk][nf], acc1[nf]);
        #pragma unroll
        for (int nf = 0; nf < 4; ++nf)
          #pragma unroll
          for (int j = 0; j < 4; ++j)
            hbuf[g * 4 + j][ncol0 + nf * 16 + r16] = (f16)tanh_fast(acc1[nf][j]);
        __syncthreads();

        // ---- phase 2: GEMM2 (K-split) + u staging ----
        f32x4 acc2 = (f32x4){0.f, 0.f, 0.f, 0.f};
        #pragma unroll
        for (int kk = 0; kk < 8; ++kk) {
            f16x8 hf = *(const f16x8*)&hbuf[r16][ks * 256 + kk * 32 + g * 8];
            acc2 = MFMA16(hf, W2F[kk], acc2);
        }
        if (ks == 1) {
            *(f32x4*)&redbuf[ns][lane * 4] = acc2;
            if (t + 1 < L) {  // write u(t+1) hi/lo (z_t already consumed pre-barrier)
                f16 ah = (f16)ua, bh = (f16)ub;
                zbuf[urow][128 + ucol]     = ah;
                zbuf[urow][128 + ucol + 1] = bh;
                zbuf[urow][160 + ucol]     = (f16)(ua - (float)ah);
                zbuf[urow][160 + ucol + 1] = (f16)(ub - (float)bh);
            }
            if (t + 2 < L) {  // prefetch u(t+2)
                const float* up = uin + (size_t)(b0 + urow) * L * U + (size_t)(t + 2) * U + ucol;
                ua = up[0]; ub = up[1];
            }
        }
        __syncthreads();

        // ---- phase 3: reduce, state update, store, z_{t+1} -> LDS ----
        if (ks == 0) {
            const f32x4 part = *(const f32x4*)&redbuf[ns][lane * 4];
            #pragma unroll
            for (int j = 0; j < 4; ++j) {
                float d = acc2[j] + part[j] + b2v;
                float s = __builtin_fmaf(0.1f, d, stateF[j]);
                stateF[j] = s;
                out[((size_t)(b0 + g * 4 + j) * L + t) * S + ns * 16 + r16] = s;
                f16 sh = (f16)s;
                zbuf[g * 4 + j][ns * 16 + r16]      = sh;
                zbuf[g * 4 + j][64 + ns * 16 + r16] = (f16)(s - (float)sh);
            }
        }
        __syncthreads();
    }
}

extern "C" void kernel_launch(void* const* d_in, const int* in_sizes, int n_in,
                              void* d_out, int out_size, void* d_ws, size_t ws_size,
                              hipStream_t stream) {
    const float* init = (const float*)d_in[0];
    const float* uin  = (const float*)d_in[1];
    const float* W1   = (const float*)d_in[2];
    const float* b1   = (const float*)d_in[3];
    const float* W2   = (const float*)d_in[4];
    const float* b2   = (const float*)d_in[5];
    euler_kernel<<<dim3(64), dim3(512), 0, stream>>>(init, uin, W1, b1, W2, b2,
                                                     (float*)d_out);
}

// Round 2
// 664.724 us; speedup vs baseline: 1.0825x; 1.0825x over previous
//
#include <hip/hip_runtime.h>
#include <hip/hip_fp16.h>

// Euler neural-ODE scan: B=1024, L=512, S=64, U=32, H=512, dt=0.1.
// 64 blocks x 512 threads (8 waves); block owns 16 batch rows for all steps.
// Both GEMMs computed TRANSPOSED (A = W^T fragments in registers, B = z/h),
// so C-fragments hold 4 consecutive output columns per lane -> packed b64
// LDS writes, float4 global stores, bank-uniform LDS traffic.
// Step = 2 phases / 2 barriers:
//   P1 (all 8 waves): z (16x192 split-f16) -> GEMM1 slice (64 H-cols/wave)
//       -> tanh -> h (f16) to LDS.
//   P2 (waves 0-3): full-K GEMM2 (two K-half accumulator chains, kept
//       separate for bit-identical association with the old reduction),
//       state update (fp32), float4 out store, state hi/lo -> LDS.
//      (waves 4-7): write u(t+1) from prefetch regs, prefetch u(t+2).
// Numerics (f16 weight rounding, split-f16 z, tanh, accumulation order) are
// bit-identical to the round-1 kernel: absmax should stay 3.25.

typedef _Float16 f16;
typedef __attribute__((ext_vector_type(4))) _Float16 f16x4;
typedef __attribute__((ext_vector_type(8))) _Float16 f16x8;
typedef __attribute__((ext_vector_type(4))) float f32x4;

#define MFMA16(a, b, c) __builtin_amdgcn_mfma_f32_16x16x32_f16((a), (b), (c), 0, 0, 0)

__device__ __forceinline__ float tanh_fast(float x) {
    float t = __builtin_amdgcn_exp2f(x * 2.885390081777927f);  // e^{2x}
    float r = __builtin_amdgcn_rcpf(t + 1.0f);
    return __builtin_fmaf(-2.0f, r, 1.0f);
}

__global__ __launch_bounds__(512, 2)
void euler_kernel(const float* __restrict__ init,
                  const float* __restrict__ uin,
                  const float* __restrict__ W1,
                  const float* __restrict__ b1,
                  const float* __restrict__ W2,
                  const float* __restrict__ b2,
                  float* __restrict__ out) {
    const int L = 512, S = 64, U = 32, H = 512;
    const int tid  = threadIdx.x;
    const int lane = tid & 63;
    const int w    = tid >> 6;      // wave 0..7
    const int g    = lane >> 4;     // k-group 0..3
    const int r16  = lane & 15;
    const int b0   = blockIdx.x * 16;

    // z K-layout (192): [state_hi(64) | state_lo(64) | u_hi(32) | u_lo(32)]
    __shared__ f16 zbuf[16][200];   // rows = batch b; stride 200 f16 = 100 dw
    __shared__ f16 hbuf[16][520];   // rows = batch b

    // ---- W1^T A-fragments (all waves): lane holds W1[k][hcol=w*64+nf*16+r16]
    f16x8 W1F[6][4];
    #pragma unroll
    for (int kk = 0; kk < 6; ++kk)
      #pragma unroll
      for (int nf = 0; nf < 4; ++nf)
        #pragma unroll
        for (int j = 0; j < 8; ++j) {
            int k  = kk * 32 + g * 8 + j;
            int kr = (k < 128) ? (k & 63) : (64 + (k & 31));  // hi/lo share rows
            W1F[kk][nf][j] = (f16)W1[kr * H + w * 64 + nf * 16 + r16];
        }
    // b1 per output row (hcol = w*64+nf*16+4g+j)
    f32x4 b1v[4];
    #pragma unroll
    for (int nf = 0; nf < 4; ++nf)
        b1v[nf] = *(const f32x4*)&b1[w * 64 + nf * 16 + g * 4];

    // ---- waves 0-3: W2^T A-fragments (full K=512), bias, state ----
    f16x8 W2F[16];
    f32x4 b2v = (f32x4){0.f, 0.f, 0.f, 0.f};
    f32x4 stateF = (f32x4){0.f, 0.f, 0.f, 0.f};
    f32x4 ua0 = (f32x4){0.f, 0.f, 0.f, 0.f}, ua1 = ua0;
    if (w < 4) {
        #pragma unroll
        for (int kk = 0; kk < 16; ++kk)
          #pragma unroll
          for (int j = 0; j < 8; ++j) {
              int k = kk * 32 + g * 8 + j;
              W2F[kk][j] = (f16)W2[k * S + w * 16 + r16];
          }
        b2v = *(const f32x4*)&b2[w * 16 + g * 4];
        stateF = *(const f32x4*)&init[(size_t)(b0 + r16) * S + w * 16 + g * 4];
        f16x4 sh, sl;
        #pragma unroll
        for (int j = 0; j < 4; ++j) {
            sh[j] = (f16)stateF[j];
            sl[j] = (f16)(stateF[j] - (float)sh[j]);
        }
        *(f16x4*)&zbuf[r16][w * 16 + g * 4]      = sh;
        *(f16x4*)&zbuf[r16][64 + w * 16 + g * 4] = sl;
    } else {
        // u staging: lane owns row b=r16, cols g*8..g*8+7
        const float* up = uin + (size_t)(b0 + r16) * L * U + g * 8;  // t=0
        f32x4 u0 = *(const f32x4*)up;
        f32x4 u1 = *(const f32x4*)(up + 4);
        f16x8 uh, ul;
        #pragma unroll
        for (int j = 0; j < 4; ++j) {
            f16 h0 = (f16)u0[j]; uh[j] = h0;     ul[j] = (f16)(u0[j] - (float)h0);
            f16 h1 = (f16)u1[j]; uh[4 + j] = h1; ul[4 + j] = (f16)(u1[j] - (float)h1);
        }
        *(f16x8*)&zbuf[r16][128 + g * 8] = uh;
        *(f16x8*)&zbuf[r16][160 + g * 8] = ul;
        ua0 = *(const f32x4*)(up + U);        // prefetch t=1
        ua1 = *(const f32x4*)(up + U + 4);
    }
    __syncthreads();

    #pragma unroll 1
    for (int t = 0; t < L; ++t) {
        // ---- P1: GEMM1 (transposed) + tanh + h -> LDS ----
        f16x8 zf[6];
        #pragma unroll
        for (int kk = 0; kk < 6; ++kk)
            zf[kk] = *(const f16x8*)&zbuf[r16][kk * 32 + g * 8];
        f32x4 acc1[4];
        #pragma unroll
        for (int nf = 0; nf < 4; ++nf) acc1[nf] = b1v[nf];
        #pragma unroll
        for (int kk = 0; kk < 6; ++kk)
          #pragma unroll
          for (int nf = 0; nf < 4; ++nf)
            acc1[nf] = MFMA16(W1F[kk][nf], zf[kk], acc1[nf]);
        #pragma unroll
        for (int nf = 0; nf < 4; ++nf) {
            f16x4 hv;
            #pragma unroll
            for (int j = 0; j < 4; ++j) hv[j] = (f16)tanh_fast(acc1[nf][j]);
            *(f16x4*)&hbuf[r16][w * 64 + nf * 16 + g * 4] = hv;
        }
        __syncthreads();

        // ---- P2 ----
        if (w < 4) {
            f32x4 accA = (f32x4){0.f, 0.f, 0.f, 0.f};
            f32x4 accB = (f32x4){0.f, 0.f, 0.f, 0.f};
            #pragma unroll
            for (int kk = 0; kk < 8; ++kk) {
                f16x8 hf = *(const f16x8*)&hbuf[r16][kk * 32 + g * 8];
                accA = MFMA16(W2F[kk], hf, accA);
            }
            #pragma unroll
            for (int kk = 8; kk < 16; ++kk) {
                f16x8 hf = *(const f16x8*)&hbuf[r16][kk * 32 + g * 8];
                accB = MFMA16(W2F[kk], hf, accB);
            }
            f16x4 sh, sl;
            #pragma unroll
            for (int j = 0; j < 4; ++j) {
                float d = (accA[j] + accB[j]) + b2v[j];
                float s = __builtin_fmaf(0.1f, d, stateF[j]);
                stateF[j] = s;
                sh[j] = (f16)s;
                sl[j] = (f16)(s - (float)sh[j]);
            }
            *(f32x4*)&out[((size_t)(b0 + r16) * L + t) * S + w * 16 + g * 4] = stateF;
            *(f16x4*)&zbuf[r16][w * 16 + g * 4]      = sh;
            *(f16x4*)&zbuf[r16][64 + w * 16 + g * 4] = sl;
        } else {
            if (t + 1 < L) {  // write u(t+1) from prefetch regs
                f16x8 uh, ul;
                #pragma unroll
                for (int j = 0; j < 4; ++j) {
                    f16 h0 = (f16)ua0[j]; uh[j] = h0;     ul[j] = (f16)(ua0[j] - (float)h0);
                    f16 h1 = (f16)ua1[j]; uh[4 + j] = h1; ul[4 + j] = (f16)(ua1[j] - (float)h1);
                }
                *(f16x8*)&zbuf[r16][128 + g * 8] = uh;
                *(f16x8*)&zbuf[r16][160 + g * 8] = ul;
            }
            if (t + 2 < L) {  // prefetch u(t+2)
                const float* up = uin + (size_t)(b0 + r16) * L * U + (size_t)(t + 2) * U + g * 8;
                ua0 = *(const f32x4*)up;
                ua1 = *(const f32x4*)(up + 4);
            }
        }
        __syncthreads();
    }
}

extern "C" void kernel_launch(void* const* d_in, const int* in_sizes, int n_in,
                              void* d_out, int out_size, void* d_ws, size_t ws_size,
                              hipStream_t stream) {
    const float* init = (const float*)d_in[0];
    const float* uin  = (const float*)d_in[1];
    const float* W1   = (const float*)d_in[2];
    const float* b1   = (const float*)d_in[3];
    const float* W2   = (const float*)d_in[4];
    const float* b2   = (const float*)d_in[5];
    euler_kernel<<<dim3(64), dim3(512), 0, stream>>>(init, uin, W1, b1, W2, b2,
                                                     (float*)d_out);
}

// Round 3
// 600.566 us; speedup vs baseline: 1.1981x; 1.1068x over previous
//
#include <hip/hip_runtime.h>
#include <hip/hip_fp16.h>

// Euler neural-ODE scan: B=1024, L=512, S=64, U=32, H=512, dt=0.1.
// 64 blocks x 512 threads (8 waves); block owns 16 batch rows for all steps.
// Round-3 structure: h NEVER goes through LDS (pi-permutation trick):
//   GEMM1 (transposed, A=W1^T frags in regs) is loaded with a permuted
//   H-column mapping  hcol(m) = w*64 + 32*(nf>>1) + 8*((m>>2)&3) + 4*(nf&1) + (m&3)
//   so each lane's tanh'd C-fragments pack directly into the B-fragments
//   GEMM2 needs for k in [w*64, w*64+64).  Wave w computes its GEMM2 K-slice
//   from its own registers; 8 f32 partials reduced through LDS by waves 0-3.
// All LDS access is chunk-linear (chunk index = const + lane) => conflict-free.
// LDS/step: z-reads 48 b128, partial-writes 32 b128, partial-reads 32 b128,
// state-z-writes 8 b64, u-writes 2 b128  (~half of round-2's volume).

typedef _Float16 f16;
typedef __attribute__((ext_vector_type(4))) _Float16 f16x4;
typedef __attribute__((ext_vector_type(8))) _Float16 f16x8;
typedef __attribute__((ext_vector_type(4))) float f32x4;

#define MFMA16(a, b, c) __builtin_amdgcn_mfma_f32_16x16x32_f16((a), (b), (c), 0, 0, 0)

__device__ __forceinline__ float tanh_fast(float x) {
    float t = __builtin_amdgcn_exp2f(x * 2.885390081777927f);  // e^{2x}
    float r = __builtin_amdgcn_rcpf(t + 1.0f);
    return __builtin_fmaf(-2.0f, r, 1.0f);
}

__global__ __launch_bounds__(512, 2)
void euler_kernel(const float* __restrict__ init,
                  const float* __restrict__ uin,
                  const float* __restrict__ W1,
                  const float* __restrict__ b1,
                  const float* __restrict__ W2,
                  const float* __restrict__ b2,
                  float* __restrict__ out) {
    const int L = 512, S = 64, U = 32, H = 512;
    const int tid  = threadIdx.x;
    const int lane = tid & 63;
    const int w    = tid >> 6;      // wave 0..7
    const int g    = lane >> 4;     // k-group 0..3
    const int r16  = lane & 15;
    const int b0   = blockIdx.x * 16;

    // z: 6 kk-tiles x 64 chunks x 8 f16.  chunk(kk,g,r16) = kk*64 + g*16 + r16
    //   kk 0,1: state_hi (k=s), kk 2,3: state_lo, kk 4: u_hi, kk 5: u_lo.
    __shared__ f16   zbuf[6 * 64 * 8];     // 6 KB
    // partials: chunk(w, sq, b) = w*256 + sq*16 + b, each f32x4 (s-quad sq, batch b)
    __shared__ float pbuf[8 * 16 * 16 * 4];  // 32 KB

    // ---- W1^T A-fragments with pi-permuted H-columns ----
    // A[m = nf*16 + r16][k = g*8 + j];  hcol = w*64 + pi(m)
    f16x8 W1F[6][4];
    #pragma unroll
    for (int kk = 0; kk < 6; ++kk)
      #pragma unroll
      for (int nf = 0; nf < 4; ++nf) {
          const int hcol = w * 64 + 32 * (nf >> 1) + 8 * (r16 >> 2) + 4 * (nf & 1) + (r16 & 3);
          #pragma unroll
          for (int j = 0; j < 8; ++j) {
              int k  = kk * 32 + g * 8 + j;
              int kr = (k < 128) ? (k & 63) : (64 + (k & 31));
              W1F[kk][nf][j] = (f16)W1[kr * H + hcol];
          }
      }
    // b1 for C rows m = nf*16 + g*4 + j  ->  hcol = w*64 + 32*(nf>>1) + 4*(nf&1) + 8*g + j
    f32x4 b1v[4];
    #pragma unroll
    for (int nf = 0; nf < 4; ++nf)
        b1v[nf] = *(const f32x4*)&b1[w * 64 + 32 * (nf >> 1) + 4 * (nf & 1) + 8 * g];

    // ---- W2^T A-fragments for this wave's K-slice k in [w*64, w*64+64) ----
    // A2[m2 = nf2*16 + r16][k]; W2F[a][nf2][j] = W2[w*64 + a*32 + g*8 + j][nf2*16 + r16]
    f16x8 W2F[2][4];
    #pragma unroll
    for (int a = 0; a < 2; ++a)
      #pragma unroll
      for (int nf2 = 0; nf2 < 4; ++nf2)
        #pragma unroll
        for (int j = 0; j < 8; ++j) {
            int k = w * 64 + a * 32 + g * 8 + j;
            W2F[a][nf2][j] = (f16)W2[k * S + nf2 * 16 + r16];
        }

    // ---- state (waves 0-3: s = w*16 + g*4 + j, batch = r16) ----
    f32x4 b2v = (f32x4){0.f, 0.f, 0.f, 0.f};
    f32x4 stateF = (f32x4){0.f, 0.f, 0.f, 0.f};
    f32x4 ua0 = (f32x4){0.f, 0.f, 0.f, 0.f}, ua1 = ua0;
    // state z-chunk addressing (hi): chunk = (w>>1)*64 + ((w&1)*2 + (g>>1))*16 + r16
    const int schunk = (w >> 1) * 64 + ((w & 1) * 2 + (g >> 1)) * 16 + r16;
    const int soff   = (g & 1) * 4;  // f16 offset within chunk

    if (w < 4) {
        b2v    = *(const f32x4*)&b2[w * 16 + g * 4];
        stateF = *(const f32x4*)&init[(size_t)(b0 + r16) * S + w * 16 + g * 4];
        f16x4 sh, sl;
        #pragma unroll
        for (int j = 0; j < 4; ++j) {
            sh[j] = (f16)stateF[j];
            sl[j] = (f16)(stateF[j] - (float)sh[j]);
        }
        *(f16x4*)&zbuf[schunk * 8 + soff]         = sh;
        *(f16x4*)&zbuf[(schunk + 128) * 8 + soff] = sl;
    } else if (w == 4 || w == 5) {
        const float* up = uin + (size_t)(b0 + r16) * L * U + g * 8;  // t=0
        f32x4 u0 = *(const f32x4*)up;
        f32x4 u1 = *(const f32x4*)(up + 4);
        f16x8 uv;
        if (w == 4) {
            #pragma unroll
            for (int j = 0; j < 4; ++j) { uv[j] = (f16)u0[j]; uv[4 + j] = (f16)u1[j]; }
            *(f16x8*)&zbuf[(256 + lane) * 8] = uv;
        } else {
            #pragma unroll
            for (int j = 0; j < 4; ++j) {
                uv[j]     = (f16)(u0[j] - (float)(f16)u0[j]);
                uv[4 + j] = (f16)(u1[j] - (float)(f16)u1[j]);
            }
            *(f16x8*)&zbuf[(320 + lane) * 8] = uv;
        }
        ua0 = *(const f32x4*)(up + U);       // prefetch t=1
        ua1 = *(const f32x4*)(up + U + 4);
    }
    __syncthreads();

    #pragma unroll 1
    for (int t = 0; t < L; ++t) {
        // ---- P1: z-read (linear), GEMM1, tanh+pack, GEMM2 slice, partial write ----
        f16x8 zf[6];
        #pragma unroll
        for (int kk = 0; kk < 6; ++kk)
            zf[kk] = *(const f16x8*)&zbuf[(kk * 64 + lane) * 8];
        f32x4 acc1[4];
        #pragma unroll
        for (int nf = 0; nf < 4; ++nf) acc1[nf] = b1v[nf];
        #pragma unroll
        for (int kk = 0; kk < 6; ++kk)
          #pragma unroll
          for (int nf = 0; nf < 4; ++nf)
            acc1[nf] = MFMA16(W1F[kk][nf], zf[kk], acc1[nf]);
        // tanh + pack: B2-frag[a] = [tanh(acc1[2a][0..3]), tanh(acc1[2a+1][0..3])]
        f16x8 hb[2];
        #pragma unroll
        for (int a = 0; a < 2; ++a)
          #pragma unroll
          for (int j8 = 0; j8 < 8; ++j8)
            hb[a][j8] = (f16)tanh_fast(acc1[a * 2 + (j8 >> 2)][j8 & 3]);
        f32x4 acc2[4];
        #pragma unroll
        for (int nf2 = 0; nf2 < 4; ++nf2) acc2[nf2] = (f32x4){0.f, 0.f, 0.f, 0.f};
        #pragma unroll
        for (int a = 0; a < 2; ++a)
          #pragma unroll
          for (int nf2 = 0; nf2 < 4; ++nf2)
            acc2[nf2] = MFMA16(W2F[a][nf2], hb[a], acc2[nf2]);
        #pragma unroll
        for (int nf2 = 0; nf2 < 4; ++nf2)
            *(f32x4*)&pbuf[(w * 256 + nf2 * 64 + lane) * 4] = acc2[nf2];
        __syncthreads();

        // ---- P2: reduce + state update (waves 0-3); u staging (waves 4,5) ----
        if (w < 4) {
            f32x4 sum = *(const f32x4*)&pbuf[(w * 64 + lane) * 4];
            #pragma unroll
            for (int ww = 1; ww < 8; ++ww) {
                f32x4 p = *(const f32x4*)&pbuf[(ww * 256 + w * 64 + lane) * 4];
                #pragma unroll
                for (int j = 0; j < 4; ++j) sum[j] += p[j];
            }
            f16x4 sh, sl;
            #pragma unroll
            for (int j = 0; j < 4; ++j) {
                float d = sum[j] + b2v[j];
                float s = __builtin_fmaf(0.1f, d, stateF[j]);
                stateF[j] = s;
                sh[j] = (f16)s;
                sl[j] = (f16)(s - (float)sh[j]);
            }
            *(f32x4*)&out[((size_t)(b0 + r16) * L + t) * S + w * 16 + g * 4] = stateF;
            *(f16x4*)&zbuf[schunk * 8 + soff]         = sh;
            *(f16x4*)&zbuf[(schunk + 128) * 8 + soff] = sl;
        } else if (w == 4 || w == 5) {
            if (t + 1 < L) {
                f16x8 uv;
                if (w == 4) {
                    #pragma unroll
                    for (int j = 0; j < 4; ++j) { uv[j] = (f16)ua0[j]; uv[4 + j] = (f16)ua1[j]; }
                    *(f16x8*)&zbuf[(256 + lane) * 8] = uv;
                } else {
                    #pragma unroll
                    for (int j = 0; j < 4; ++j) {
                        uv[j]     = (f16)(ua0[j] - (float)(f16)ua0[j]);
                        uv[4 + j] = (f16)(ua1[j] - (float)(f16)ua1[j]);
                    }
                    *(f16x8*)&zbuf[(320 + lane) * 8] = uv;
                }
            }
            if (t + 2 < L) {
                const float* up = uin + (size_t)(b0 + r16) * L * U + (size_t)(t + 2) * U + g * 8;
                ua0 = *(const f32x4*)up;
                ua1 = *(const f32x4*)(up + 4);
            }
        }
        __syncthreads();
    }
}

extern "C" void kernel_launch(void* const* d_in, const int* in_sizes, int n_in,
                              void* d_out, int out_size, void* d_ws, size_t ws_size,
                              hipStream_t stream) {
    const float* init = (const float*)d_in[0];
    const float* uin  = (const float*)d_in[1];
    const float* W1   = (const float*)d_in[2];
    const float* b1   = (const float*)d_in[3];
    const float* W2   = (const float*)d_in[4];
    const float* b2   = (const float*)d_in[5];
    euler_kernel<<<dim3(64), dim3(512), 0, stream>>>(init, uin, W1, b1, W2, b2,
                                                     (float*)d_out);
}